// Round 4
// baseline (321.389 us; speedup 1.0000x reference)
//
#include <hip/hip_runtime.h>

// SJLT projection: out[b, idx[d,j]] += x[b,d] * sign(d,j), * 1/sqrt(4)
// B=64, D=524288, P=8192, C=4.
//
// Model so far (R1-R9):
//  - LDS fp atomics (ds_add_f32): ~3.2 cyc/LANE serialized -> never for data.
//  - Random 4B global stores: 64B HBM write-back EACH. L2 is no-write-
//    allocate AND pretouch does NOT help (R9: memset before scatter left
//    WRITE at 187 MB). Spatial partitioning doesn't help either (R8).
//    => never issue scattered small global stores; stage in LDS and write
//    coalesced chunks.
//  - Inputs L3-resident across iterations (FETCH 74 MB < 134 MB x).
//  - Fixed harness overhead ~105 us; kernel work is what we optimize.
//  - R9 best = 285.8 us: memset + fused_tx_scatter(101, store-drain) +
//    gather4(~65, LDS-staged out, A/B dbuf).
// R10: remove ALL scattered stores. transpose (pure) + binA (coarse bin,
// 256 buckets x 32p, LDS compact -> coalesced chunk writes, deterministic
// per-(bucket,block) regions, no atomics/memsets) + gather5 (fine-bin in
// LDS CSR + proven per-p-wave gather, 2 blocks/CU).

constexpr int BATCH = 64;
constexpr int DIM   = 524288;
constexpr int PROJ  = 8192;
constexpr int NENT  = DIM * 4;          // 2,097,152 entries
constexpr int CAP   = 384;              // per-p cap (proven by R7/R9 passing)

constexpr int NBLKA = 256;              // binA blocks
constexpr int EPB   = NENT / NBLKA;     // 8192 entries per binA block
constexpr int NBUCK = 256;              // coarse buckets
constexpr int BUCKP = PROJ / NBUCK;     // 32 p per bucket
constexpr int CAPB  = 80;               // per (bucket, blockA) cap: mean 32, +8.5 sigma

// ------------------------------------------------ helpers
__device__ __forceinline__ uint32_t f2bf(float f) {   // RNE f32 -> bf16 bits
    uint32_t u = __float_as_uint(f);
    return (u + 0x7fffu + ((u >> 16) & 1u)) >> 16;
}

// ==================== R10 pass 1: pure transpose ========================
// Block owns 64 d's. Reads x tile (64b x 64d) via float4, writes xT rows
// (bf16-pair packed, scale 0.5 folded) via dwordx4 (16B/lane).
__global__ __launch_bounds__(256) void transpose_kernel(
    const float* __restrict__ x, uint32_t* __restrict__ xT)
{
    __shared__ float tile[64][65];
    const int d0 = blockIdx.x * 64;
    const int t  = threadIdx.x;

    const int c  = t & 15;          // float4 column
    const int r0 = t >> 4;          // row 0..15
    float4 v[4];
#pragma unroll
    for (int it = 0; it < 4; ++it) {
        int b = it * 16 + r0;
        v[it] = *reinterpret_cast<const float4*>(&x[(size_t)b * DIM + d0 + 4 * c]);
    }
#pragma unroll
    for (int it = 0; it < 4; ++it) {
        int b = it * 16 + r0;
        tile[b][4 * c + 0] = v[it].x;
        tile[b][4 * c + 1] = v[it].y;
        tile[b][4 * c + 2] = v[it].z;
        tile[b][4 * c + 3] = v[it].w;
    }
    __syncthreads();

    const int a  = t & 7;
    const int dr = t >> 3;               // 0..31
#pragma unroll
    for (int pass = 0; pass < 2; ++pass) {
        const int dl = pass * 32 + dr;
        uint4 wv;
        uint32_t* wq = reinterpret_cast<uint32_t*>(&wv);
#pragma unroll
        for (int q = 0; q < 4; ++q) {
            const int k = 4 * a + q;     // u32 index = batch pair (2k, 2k+1)
            uint32_t lo = f2bf(tile[2 * k + 0][dl] * 0.5f);
            uint32_t hi = f2bf(tile[2 * k + 1][dl] * 0.5f);
            wq[q] = lo | (hi << 16);
        }
        *reinterpret_cast<uint4*>(&xT[(size_t)(d0 + dl) * 32 + 4 * a]) = wv;
    }
}

// ==================== R10 pass 2: coarse binning ========================
// 256 blocks x 1024 threads, 8192 entries each. Count -> scan -> compact
// into LDS staging grouped by bucket (p>>5), then write each bucket's
// chunk coalesced to coarse[(bucket*NBLKA + blk)*CAPB]. Payload (26 bits):
// (p&31)<<20 | d<<1 | s. cntAB[blk*NBUCK + b] = chunk count (coalesced).
__global__ __launch_bounds__(1024) void binA_kernel(
    const int4* __restrict__ idx4, const int4* __restrict__ sgn4,
    uint32_t* __restrict__ cntAB, uint32_t* __restrict__ coarse)
{
    __shared__ uint32_t cntL[NBUCK], offL[NBUCK], curL[NBUCK];
    __shared__ uint32_t wsumA[4];
    __shared__ uint32_t staging[EPB];        // 32 KB
    const int t    = threadIdx.x;
    const int lane = t & 63;
    const int blk  = blockIdx.x;

    if (t < NBUCK) cntL[t] = 0;
    __syncthreads();

    // load 2 int4 rows of idx/sgn -> 8 entries/thread (coalesced)
    int4 iv[2], sv[2];
    int  dd[2];
#pragma unroll
    for (int j = 0; j < 2; ++j) {
        int d = blk * 2048 + j * 1024 + t;
        dd[j] = d;
        iv[j] = idx4[d];
        sv[j] = sgn4[d];
    }
    // count
#pragma unroll
    for (int j = 0; j < 2; ++j) {
        atomicAdd(&cntL[(uint32_t)iv[j].x >> 5], 1u);
        atomicAdd(&cntL[(uint32_t)iv[j].y >> 5], 1u);
        atomicAdd(&cntL[(uint32_t)iv[j].z >> 5], 1u);
        atomicAdd(&cntL[(uint32_t)iv[j].w >> 5], 1u);
    }
    __syncthreads();
    // exclusive scan of cntL[256] (first 4 waves)
    uint32_t v = 0, s = 0;
    if (t < NBUCK) {
        s = cntL[t]; v = s;
#pragma unroll
        for (int off = 1; off < 64; off <<= 1) {
            uint32_t u = __shfl_up(v, off);
            if (lane >= off) v += u;
        }
        if (lane == 63) wsumA[t >> 6] = v;
    }
    __syncthreads();
    if (t < NBUCK) {
        uint32_t wb = 0;
        for (int w0 = 0; w0 < (t >> 6); ++w0) wb += wsumA[w0];
        uint32_t ex = wb + v - s;
        offL[t] = ex;
        curL[t] = ex;
    }
    __syncthreads();
    // place into staging grouped by bucket
#pragma unroll
    for (int j = 0; j < 2; ++j) {
        const uint32_t dv = (uint32_t)dd[j] << 1;
        int p, ss;
        uint32_t b, sl;
        p = iv[j].x; ss = sv[j].x & 1; b = (uint32_t)p >> 5;
        sl = atomicAdd(&curL[b], 1u);
        staging[sl] = ((uint32_t)(p & 31) << 20) | dv | (uint32_t)ss;
        p = iv[j].y; ss = sv[j].y & 1; b = (uint32_t)p >> 5;
        sl = atomicAdd(&curL[b], 1u);
        staging[sl] = ((uint32_t)(p & 31) << 20) | dv | (uint32_t)ss;
        p = iv[j].z; ss = sv[j].z & 1; b = (uint32_t)p >> 5;
        sl = atomicAdd(&curL[b], 1u);
        staging[sl] = ((uint32_t)(p & 31) << 20) | dv | (uint32_t)ss;
        p = iv[j].w; ss = sv[j].w & 1; b = (uint32_t)p >> 5;
        sl = atomicAdd(&curL[b], 1u);
        staging[sl] = ((uint32_t)(p & 31) << 20) | dv | (uint32_t)ss;
    }
    __syncthreads();
    // write chunks coalesced: wave w copies buckets w*16 .. w*16+15
    const int w = t >> 6;
    for (int i = 0; i < NBUCK / 16; ++i) {
        const int b = w * (NBUCK / 16) + i;
        const uint32_t c   = min(cntL[b], (uint32_t)CAPB);
        const uint32_t src = offL[b];
        uint32_t* dst = coarse + ((size_t)b * NBLKA + blk) * CAPB;
        for (uint32_t j2 = lane; j2 < c; j2 += 64) dst[j2] = staging[src + j2];
    }
    if (t < NBUCK) cntAB[(size_t)blk * NBUCK + t] = min(cntL[t], (uint32_t)CAPB);
}

// ==================== R10 pass 3: fine-bin + gather =====================
// Block = one bucket (32 p), 1024 threads, 2 blocks/CU (58.7 KB LDS).
// Phase 1: read this bucket's 256 chunks, LDS-atomic slot into LDS CSR.
// Phase 2: per-p wave gather (entries from LDS), obuf-staged out writes.
__global__ __launch_bounds__(1024) void gather5_kernel(
    const uint32_t* __restrict__ coarse, const uint32_t* __restrict__ cntAB,
    const uint32_t* __restrict__ xT, float* __restrict__ out)
{
    __shared__ uint32_t csr[BUCKP * CAP];    // 49152 B
    __shared__ uint32_t cntF[BUCKP];
    __shared__ uint32_t cAB[NBLKA];          // 1 KB
    __shared__ float    obuf[64][BUCKP + 1]; // 8448 B
    const int t      = threadIdx.x;
    const int w      = t >> 6;               // 0..15
    const int lane   = t & 63;
    const int bucket = blockIdx.x;

    if (t < BUCKP) cntF[t] = 0;
    if (t < NBLKA) cAB[t] = cntAB[(size_t)t * NBUCK + bucket];
    __syncthreads();

    // fine-bin: wave w handles chunks j = w*16 .. w*16+15
    for (int i = 0; i < NBLKA / 16; ++i) {
        const int j = w * (NBLKA / 16) + i;
        const uint32_t c = cAB[j];
        const uint32_t* src = coarse + ((size_t)bucket * NBLKA + j) * CAPB;
        for (uint32_t i2 = lane; i2 < c; i2 += 64) {
            const uint32_t pay = src[i2];
            const uint32_t pl  = (pay >> 20) & 31u;
            const uint32_t sl  = atomicAdd(&cntF[pl], 1u);
            csr[pl * CAP + sl] = pay & 0xFFFFFu;   // d<<1 | s
        }
    }
    __syncthreads();

    // gather: wave w -> p_local w and w+16
    const int half = lane >> 5;     // 0: even entries, 1: odd entries
    const int k    = lane & 31;     // u32 index within xT row (2 batch elems)
#pragma unroll
    for (int pi = 0; pi < 2; ++pi) {
        const int pl = w + pi * 16;
        const uint32_t n = cntF[pl];
        const uint32_t* e = &csr[pl * CAP];
        float acc0 = 0.f, acc1 = 0.f;
        uint32_t base = 0;
        for (; base + 8 <= n; base += 8) {
            uint32_t e8[8];
#pragma unroll
            for (int q = 0; q < 8; ++q) e8[q] = e[base + q];
#pragma unroll
            for (int q = 0; q < 8; q += 2) {
                uint32_t sel = half ? e8[q + 1] : e8[q];
                uint32_t u = xT[(size_t)(sel >> 1) * 32 + k];  // 128B/half-wave
                u ^= (sel & 1u) ? 0u : 0x80008000u;            // s=0 -> negate
                acc0 += __uint_as_float(u << 16);              // b = 2k
                acc1 += __uint_as_float(u & 0xffff0000u);      // b = 2k+1
            }
        }
        for (; base < n; base += 2) {
            uint32_t eA = e[base];
            uint32_t eB = (base + 1 < n) ? e[base + 1] : 0u;
            uint32_t sel   = half ? eB : eA;
            bool     valid = (base + (uint32_t)half) < n;
            uint32_t u = 0u;
            if (valid) {
                u = xT[(size_t)(sel >> 1) * 32 + k];
                u ^= (sel & 1u) ? 0u : 0x80008000u;
            }
            acc0 += __uint_as_float(u << 16);
            acc1 += __uint_as_float(u & 0xffff0000u);
        }
        acc0 += __shfl_xor(acc0, 32);
        acc1 += __shfl_xor(acc1, 32);
        if (half == 0) {
            obuf[2 * k + 0][pl] = acc0;
            obuf[2 * k + 1][pl] = acc1;
        }
    }
    __syncthreads();
    // out: 64 rows x 32 p = two full 64B lines per row
    const int b = t >> 4, q = t & 15;
    float2 v2;
    v2.x = obuf[b][2 * q + 0];
    v2.y = obuf[b][2 * q + 1];
    *reinterpret_cast<float2*>(&out[(size_t)b * PROJ + bucket * BUCKP + 2 * q]) = v2;
}

// ==================== R9 fallback: fused scatter + gather4 ==============
__global__ __launch_bounds__(256) void fused_tx_scatter(
    const float* __restrict__ x, const int* __restrict__ idx,
    const int* __restrict__ sgn, uint32_t* __restrict__ cnt,
    uint32_t* __restrict__ entries, uint32_t* __restrict__ xT)
{
    __shared__ float tile[64][65];
    const int d0 = blockIdx.x * 64;
    const int t  = threadIdx.x;

    const int e = (d0 << 2) + t;
    const int p = idx[e];
    const int s = sgn[e] & 1;

    const int c  = t & 15;
    const int r0 = t >> 4;
    float4 v[4];
#pragma unroll
    for (int it = 0; it < 4; ++it) {
        int b = it * 16 + r0;
        v[it] = *reinterpret_cast<const float4*>(&x[(size_t)b * DIM + d0 + 4 * c]);
    }
    {
        uint32_t dv   = ((uint32_t)(d0 + (t >> 2)) << 1) | (uint32_t)s;
        uint32_t slot = atomicAdd(&cnt[p], 1u);
        entries[(uint32_t)p * (uint32_t)CAP + slot] = dv;
    }
#pragma unroll
    for (int it = 0; it < 4; ++it) {
        int b = it * 16 + r0;
        tile[b][4 * c + 0] = v[it].x;
        tile[b][4 * c + 1] = v[it].y;
        tile[b][4 * c + 2] = v[it].z;
        tile[b][4 * c + 3] = v[it].w;
    }
    __syncthreads();
    const int a  = t & 7;
    const int dr = t >> 3;
#pragma unroll
    for (int pass = 0; pass < 2; ++pass) {
        const int dl = pass * 32 + dr;
        uint4 wv;
        uint32_t* wq = reinterpret_cast<uint32_t*>(&wv);
#pragma unroll
        for (int q = 0; q < 4; ++q) {
            const int k = 4 * a + q;
            uint32_t lo = f2bf(tile[2 * k + 0][dl] * 0.5f);
            uint32_t hi = f2bf(tile[2 * k + 1][dl] * 0.5f);
            wq[q] = lo | (hi << 16);
        }
        *reinterpret_cast<uint4*>(&xT[(size_t)(d0 + dl) * 32 + 4 * a]) = wv;
    }
}

__device__ __forceinline__ void proc8(const uint32_t* __restrict__ e,
    const uint32_t* __restrict__ xT, int half, int k,
    float& acc0, float& acc1)
{
#pragma unroll
    for (int t = 0; t < 8; t += 2) {
        uint32_t sel = half ? e[t + 1] : e[t];
        uint32_t u = xT[(size_t)(sel >> 1) * 32 + k];
        u ^= (sel & 1u) ? 0u : 0x80008000u;
        acc0 += __uint_as_float(u << 16);
        acc1 += __uint_as_float(u & 0xffff0000u);
    }
}

__global__ __launch_bounds__(1024) void gather4_kernel(
    const uint32_t* __restrict__ entries, const uint32_t* __restrict__ cnt,
    const uint32_t* __restrict__ xT, float* __restrict__ out)
{
    __shared__ float obuf[64][17];
    const int w    = threadIdx.x >> 6;
    const int lane = threadIdx.x & 63;
    const int p    = __builtin_amdgcn_readfirstlane(blockIdx.x * 16 + w);
    const uint32_t n  = __builtin_amdgcn_readfirstlane(cnt[p]);
    const uint32_t e0 = (uint32_t)p * (uint32_t)CAP;

    const int half = lane >> 5;
    const int k    = lane & 31;
    float acc0 = 0.f, acc1 = 0.f;

    uint32_t A[8], B[8];
    uint32_t base = 0;
    if (n >= 8) {
#pragma unroll
        for (int t = 0; t < 8; ++t) A[t] = entries[e0 + t];
    }
    for (; base + 24 <= n; base += 16) {
#pragma unroll
        for (int t = 0; t < 8; ++t) B[t] = entries[e0 + base + 8 + t];
        proc8(A, xT, half, k, acc0, acc1);
#pragma unroll
        for (int t = 0; t < 8; ++t) A[t] = entries[e0 + base + 16 + t];
        proc8(B, xT, half, k, acc0, acc1);
    }
    if (base + 16 <= n) {
#pragma unroll
        for (int t = 0; t < 8; ++t) B[t] = entries[e0 + base + 8 + t];
        proc8(A, xT, half, k, acc0, acc1);
        proc8(B, xT, half, k, acc0, acc1);
        base += 16;
    } else if (base + 8 <= n) {
        proc8(A, xT, half, k, acc0, acc1);
        base += 8;
    }
    for (; base < n; base += 2) {
        uint32_t eA = entries[e0 + base];
        uint32_t eB = (base + 1 < n) ? entries[e0 + base + 1] : 0u;
        uint32_t sel   = half ? eB : eA;
        bool     valid = (base + (uint32_t)half) < n;
        uint32_t u = 0u;
        if (valid) {
            u = xT[(size_t)(sel >> 1) * 32 + k];
            u ^= (sel & 1u) ? 0u : 0x80008000u;
        }
        acc0 += __uint_as_float(u << 16);
        acc1 += __uint_as_float(u & 0xffff0000u);
    }
    acc0 += __shfl_xor(acc0, 32);
    acc1 += __shfl_xor(acc1, 32);
    if (half == 0) {
        obuf[2 * k + 0][w] = acc0;
        obuf[2 * k + 1][w] = acc1;
    }
    __syncthreads();
    const int t = threadIdx.x;
    if (t < 256) {
        const int b = t >> 2, q = t & 3;
        float4 v;
        v.x = obuf[b][4 * q + 0];
        v.y = obuf[b][4 * q + 1];
        v.z = obuf[b][4 * q + 2];
        v.w = obuf[b][4 * q + 3];
        *reinterpret_cast<float4*>(&out[(size_t)b * PROJ + blockIdx.x * 16 + 4 * q]) = v;
    }
}

// ------------------------------------------------- fallback (R3 scatter)
__device__ __forceinline__ void lds_fadd(uint32_t byte_addr, float v) {
    asm volatile("ds_add_f32 %0, %1" :: "v"(byte_addr), "v"(v) : "memory");
}
__device__ __forceinline__ void lds_fadd_off32k(uint32_t byte_addr, float v) {
    asm volatile("ds_add_f32 %0, %1 offset:32768" :: "v"(byte_addr), "v"(v) : "memory");
}

__global__ __launch_bounds__(1024) void sjlt_scatter(
    const float* __restrict__ x, const int4* __restrict__ idx4,
    const int4* __restrict__ sgn4, float* __restrict__ out)
{
    __shared__ float acc[4 * PROJ];
    for (int i = threadIdx.x; i < 4 * PROJ; i += 1024) acc[i] = 0.0f;
    __syncthreads();
    const int row0 = blockIdx.y * 4;
    const int dbeg = blockIdx.x * (DIM / 16);
    const uint32_t accBase = (uint32_t)(uintptr_t)(&acc[0]);
    const float* xr0 = x + (size_t)(row0 + 0) * DIM;
    const float* xr1 = x + (size_t)(row0 + 1) * DIM;
    const float* xr2 = x + (size_t)(row0 + 2) * DIM;
    const float* xr3 = x + (size_t)(row0 + 3) * DIM;
    for (int d = dbeg + (int)threadIdx.x; d < dbeg + DIM / 16; d += 1024) {
        const int4 iv = idx4[d];
        const int4 sv = sgn4[d];
        const uint32_t u0 = __float_as_uint(xr0[d]);
        const uint32_t u1 = __float_as_uint(xr1[d]);
        const uint32_t u2 = __float_as_uint(xr2[d]);
        const uint32_t u3 = __float_as_uint(xr3[d]);
        const int p[4] = {iv.x, iv.y, iv.z, iv.w};
        const int s[4] = {sv.x, sv.y, sv.z, sv.w};
#pragma unroll
        for (int j = 0; j < 4; ++j) {
            const uint32_t flip = (uint32_t)(s[j] ^ 1) << 31;
            const uint32_t a01  = accBase + ((uint32_t)p[j] << 2);
            const uint32_t a23  = a01 + 2u * 32768u;
            lds_fadd        (a01, __uint_as_float(u0 ^ flip));
            lds_fadd_off32k (a01, __uint_as_float(u1 ^ flip));
            lds_fadd        (a23, __uint_as_float(u2 ^ flip));
            lds_fadd_off32k (a23, __uint_as_float(u3 ^ flip));
        }
    }
    __syncthreads();
    for (int i = threadIdx.x; i < 4 * PROJ; i += 1024) {
        const int r  = i >> 13;
        const int pp = i & (PROJ - 1);
        unsafeAtomicAdd(&out[(size_t)(row0 + r) * PROJ + pp], acc[i] * 0.5f);
    }
}

// --------------------------------------------------------------- launch
extern "C" void kernel_launch(void* const* d_in, const int* in_sizes, int n_in,
                              void* d_out, int out_size, void* d_ws, size_t ws_size,
                              hipStream_t stream) {
    const float* x   = (const float*)d_in[0];
    const int4*  idx = (const int4*) d_in[1];
    const int4*  sgn = (const int4*) d_in[2];
    float*       out = (float*)d_out;

    // R10 layout: cntAB[256*256] | coarse[256*256*80] | xT[DIM*32] = 88,342,528 B
    const size_t need_r10 = ((size_t)NBLKA * NBUCK
                           + (size_t)NBUCK * NBLKA * CAPB
                           + (size_t)DIM * 32) * 4;
    // R9 layout: cnt[PROJ] | entries[PROJ*CAP] | xT[DIM*32]       = 79,724,544 B
    const size_t need_r9  = ((size_t)PROJ + (size_t)PROJ * CAP + (size_t)DIM * 32) * 4;

    if (ws_size >= need_r10) {
        uint32_t* cntAB  = (uint32_t*)d_ws;
        uint32_t* coarse = cntAB + (size_t)NBLKA * NBUCK;
        uint32_t* xT     = coarse + (size_t)NBUCK * NBLKA * CAPB;

        // no memsets needed: cntAB fully written by binA; LDS counters
        // zeroed in-kernel; coarse padding beyond counts never read.
        transpose_kernel<<<DIM / 64, 256, 0, stream>>>(x, xT);
        binA_kernel     <<<NBLKA,    1024, 0, stream>>>(idx, sgn, cntAB, coarse);
        gather5_kernel  <<<NBUCK,    1024, 0, stream>>>(coarse, cntAB, xT, out);
    } else if (ws_size >= need_r9) {
        uint32_t* cnt     = (uint32_t*)d_ws;
        uint32_t* entries = cnt + PROJ;
        uint32_t* xT      = entries + (size_t)PROJ * CAP;

        hipMemsetAsync(cnt, 0, PROJ * sizeof(uint32_t), stream);
        fused_tx_scatter<<<DIM / 64, 256, 0, stream>>>(
            x, (const int*)idx, (const int*)sgn, cnt, entries, xT);
        gather4_kernel<<<PROJ / 16, 1024, 0, stream>>>(entries, cnt, xT, out);
    } else {
        // ws too small: R3 LDS-scatter path (passes at ~830 us)
        hipMemsetAsync(d_out, 0, (size_t)out_size * sizeof(float), stream);
        dim3 grid(16, 16);
        sjlt_scatter<<<grid, 1024, 0, stream>>>(x, idx, sgn, out);
    }
}

// Round 5
// 305.533 us; speedup vs baseline: 1.0519x; 1.0519x over previous
//
#include <hip/hip_runtime.h>

// SJLT projection: out[b, idx[d,j]] += x[b,d] * sign(d,j), * 1/sqrt(4)
// B=64, D=524288, P=8192, C=4.
//
// Model so far (R1-R10):
//  - LDS fp atomics (ds_add_f32): ~3.2 cyc/LANE serialized -> never for data.
//  - Random 4B global stores: 64B HBM write-back EACH. L2 no-write-allocate;
//    pretouch does NOT help (R9); spatial partitioning does NOT help (R8).
//    => only LDS-staged coalesced chunk writes avoid the 10x inflation.
//  - Inputs + xT largely L3-resident (gather FETCH 132 MB vs 268 logical).
//  - Fixed harness overhead ~110 us; controllable kernel budget ~175 us (R9).
//  - R10 (transpose + binA + gather5) = 321: gather5 was 107 us because
//    grid=256 -> 1 block/CU -> 16 waves (Occ 41%) + half-idle fine-bin lanes.
// R11: same two-level structure, gather parallelism fixed: 512 blocks
// (half-bucket each, 16 p), 32 waves/CU, half-wave-per-chunk fine-bin,
// one p per wave in phase 2 (gather4's proven inner loop). Transpose and
// binA unchanged -> their true costs become visible in top-5 this round.

constexpr int BATCH = 64;
constexpr int DIM   = 524288;
constexpr int PROJ  = 8192;
constexpr int NENT  = DIM * 4;          // 2,097,152 entries
constexpr int CAP   = 384;              // per-p cap (proven R7/R9/R10)

constexpr int NBLKA = 256;              // binA blocks
constexpr int EPB   = NENT / NBLKA;     // 8192 entries per binA block
constexpr int NBUCK = 256;              // coarse buckets
constexpr int BUCKP = PROJ / NBUCK;     // 32 p per bucket
constexpr int CAPB  = 80;               // per (bucket, blockA) cap: mean 32

// ------------------------------------------------ helpers
__device__ __forceinline__ uint32_t f2bf(float f) {   // RNE f32 -> bf16 bits
    uint32_t u = __float_as_uint(f);
    return (u + 0x7fffu + ((u >> 16) & 1u)) >> 16;
}

// ==================== pass 1: pure transpose ============================
// Block owns 64 d's. Reads x tile (64b x 64d) via float4, writes xT rows
// (bf16-pair packed, scale 0.5 folded) via dwordx4 (16B/lane).
__global__ __launch_bounds__(256) void transpose_kernel(
    const float* __restrict__ x, uint32_t* __restrict__ xT)
{
    __shared__ float tile[64][65];
    const int d0 = blockIdx.x * 64;
    const int t  = threadIdx.x;

    const int c  = t & 15;          // float4 column
    const int r0 = t >> 4;          // row 0..15
    float4 v[4];
#pragma unroll
    for (int it = 0; it < 4; ++it) {
        int b = it * 16 + r0;
        v[it] = *reinterpret_cast<const float4*>(&x[(size_t)b * DIM + d0 + 4 * c]);
    }
#pragma unroll
    for (int it = 0; it < 4; ++it) {
        int b = it * 16 + r0;
        tile[b][4 * c + 0] = v[it].x;
        tile[b][4 * c + 1] = v[it].y;
        tile[b][4 * c + 2] = v[it].z;
        tile[b][4 * c + 3] = v[it].w;
    }
    __syncthreads();

    const int a  = t & 7;
    const int dr = t >> 3;               // 0..31
#pragma unroll
    for (int pass = 0; pass < 2; ++pass) {
        const int dl = pass * 32 + dr;
        uint4 wv;
        uint32_t* wq = reinterpret_cast<uint32_t*>(&wv);
#pragma unroll
        for (int q = 0; q < 4; ++q) {
            const int k = 4 * a + q;     // u32 index = batch pair (2k, 2k+1)
            uint32_t lo = f2bf(tile[2 * k + 0][dl] * 0.5f);
            uint32_t hi = f2bf(tile[2 * k + 1][dl] * 0.5f);
            wq[q] = lo | (hi << 16);
        }
        *reinterpret_cast<uint4*>(&xT[(size_t)(d0 + dl) * 32 + 4 * a]) = wv;
    }
}

// ==================== pass 2: coarse binning ============================
// 256 blocks x 1024 threads, 8192 entries each. Count -> scan -> compact
// into LDS staging grouped by bucket (p>>5), then write each bucket's
// chunk coalesced to coarse[(bucket*NBLKA + blk)*CAPB]. Payload (25 bits):
// (p&31)<<20 | d<<1 | s. cntAB[blk*NBUCK + b] = chunk count (coalesced).
__global__ __launch_bounds__(1024) void binA_kernel(
    const int4* __restrict__ idx4, const int4* __restrict__ sgn4,
    uint32_t* __restrict__ cntAB, uint32_t* __restrict__ coarse)
{
    __shared__ uint32_t cntL[NBUCK], offL[NBUCK], curL[NBUCK];
    __shared__ uint32_t wsumA[4];
    __shared__ uint32_t staging[EPB];        // 32 KB
    const int t    = threadIdx.x;
    const int lane = t & 63;
    const int blk  = blockIdx.x;

    if (t < NBUCK) cntL[t] = 0;
    __syncthreads();

    // load 2 int4 rows of idx/sgn -> 8 entries/thread (coalesced)
    int4 iv[2], sv[2];
    int  dd[2];
#pragma unroll
    for (int j = 0; j < 2; ++j) {
        int d = blk * 2048 + j * 1024 + t;
        dd[j] = d;
        iv[j] = idx4[d];
        sv[j] = sgn4[d];
    }
#pragma unroll
    for (int j = 0; j < 2; ++j) {
        atomicAdd(&cntL[(uint32_t)iv[j].x >> 5], 1u);
        atomicAdd(&cntL[(uint32_t)iv[j].y >> 5], 1u);
        atomicAdd(&cntL[(uint32_t)iv[j].z >> 5], 1u);
        atomicAdd(&cntL[(uint32_t)iv[j].w >> 5], 1u);
    }
    __syncthreads();
    // exclusive scan of cntL[256] (first 4 waves)
    uint32_t v = 0, s = 0;
    if (t < NBUCK) {
        s = cntL[t]; v = s;
#pragma unroll
        for (int off = 1; off < 64; off <<= 1) {
            uint32_t u = __shfl_up(v, off);
            if (lane >= off) v += u;
        }
        if (lane == 63) wsumA[t >> 6] = v;
    }
    __syncthreads();
    if (t < NBUCK) {
        uint32_t wb = 0;
        for (int w0 = 0; w0 < (t >> 6); ++w0) wb += wsumA[w0];
        uint32_t ex = wb + v - s;
        offL[t] = ex;
        curL[t] = ex;
    }
    __syncthreads();
    // place into staging grouped by bucket
#pragma unroll
    for (int j = 0; j < 2; ++j) {
        const uint32_t dv = (uint32_t)dd[j] << 1;
        int p, ss;
        uint32_t b, sl;
        p = iv[j].x; ss = sv[j].x & 1; b = (uint32_t)p >> 5;
        sl = atomicAdd(&curL[b], 1u);
        staging[sl] = ((uint32_t)(p & 31) << 20) | dv | (uint32_t)ss;
        p = iv[j].y; ss = sv[j].y & 1; b = (uint32_t)p >> 5;
        sl = atomicAdd(&curL[b], 1u);
        staging[sl] = ((uint32_t)(p & 31) << 20) | dv | (uint32_t)ss;
        p = iv[j].z; ss = sv[j].z & 1; b = (uint32_t)p >> 5;
        sl = atomicAdd(&curL[b], 1u);
        staging[sl] = ((uint32_t)(p & 31) << 20) | dv | (uint32_t)ss;
        p = iv[j].w; ss = sv[j].w & 1; b = (uint32_t)p >> 5;
        sl = atomicAdd(&curL[b], 1u);
        staging[sl] = ((uint32_t)(p & 31) << 20) | dv | (uint32_t)ss;
    }
    __syncthreads();
    // write chunks coalesced: wave w copies buckets w*16 .. w*16+15
    const int w = t >> 6;
    for (int i = 0; i < NBUCK / 16; ++i) {
        const int b = w * (NBUCK / 16) + i;
        const uint32_t c   = min(cntL[b], (uint32_t)CAPB);
        const uint32_t src = offL[b];
        uint32_t* dst = coarse + ((size_t)b * NBLKA + blk) * CAPB;
        for (uint32_t j2 = lane; j2 < c; j2 += 64) dst[j2] = staging[src + j2];
    }
    if (t < NBUCK) cntAB[(size_t)blk * NBUCK + t] = min(cntL[t], (uint32_t)CAPB);
}

// ==================== pass 3: fine-bin + gather (half-bucket) ===========
// 512 blocks x 1024 threads; block = half bucket (16 p), 2 blocks/CU ->
// 32 waves/CU. Phase 1: half-wave per chunk (32 lanes ~ mean chunk 32),
// keep entries for this half's 16 p, LDS-atomic slot into 16-row LDS CSR.
// Phase 2: wave w gathers p_local w (gather4's proven inner loop, entries
// from LDS). Output staged in obuf, written as full 64B lines.
__global__ __launch_bounds__(1024) void gather6_kernel(
    const uint32_t* __restrict__ coarse, const uint32_t* __restrict__ cntAB,
    const uint32_t* __restrict__ xT, float* __restrict__ out)
{
    __shared__ uint32_t csr[16 * CAP];       // 24576 B
    __shared__ uint32_t cntF[16];
    __shared__ uint32_t cAB[NBLKA];          // 1 KB
    __shared__ float    obuf[64][17];        // 4352 B
    const int t       = threadIdx.x;
    const int w       = t >> 6;              // 0..15
    const int lane    = t & 63;
    const int bucket  = blockIdx.x >> 1;
    const int halfsel = blockIdx.x & 1;

    if (t < 16) cntF[t] = 0;
    if (t < NBLKA) cAB[t] = cntAB[(size_t)t * NBUCK + bucket];
    __syncthreads();

    // fine-bin: half-wave hw handles chunks hw*8 .. hw*8+7
    const int hw = t >> 5;                   // 0..31
    const int l  = t & 31;
    for (int i = 0; i < NBLKA / 32; ++i) {
        const int j = hw * (NBLKA / 32) + i;
        const uint32_t c = cAB[j];
        const uint32_t* src = coarse + ((size_t)bucket * NBLKA + j) * CAPB;
        for (uint32_t i2 = l; i2 < c; i2 += 32) {
            const uint32_t pay = src[i2];
            const uint32_t pg  = (pay >> 20) & 31u;
            if ((int)(pg >> 4) == halfsel) {
                const uint32_t pl = pg & 15u;
                const uint32_t sl = atomicAdd(&cntF[pl], 1u);
                csr[pl * CAP + sl] = pay & 0xFFFFFu;   // d<<1 | s
            }
        }
    }
    __syncthreads();

    // gather: wave w -> p_local w
    const int half = lane >> 5;     // 0: even entries, 1: odd entries
    const int k    = lane & 31;     // u32 index within xT row (2 batch elems)
    const uint32_t n = cntF[w];
    const uint32_t* e = &csr[w * CAP];
    float acc0 = 0.f, acc1 = 0.f;
    uint32_t base = 0;
    for (; base + 8 <= n; base += 8) {
        uint32_t e8[8];
#pragma unroll
        for (int q = 0; q < 8; ++q) e8[q] = e[base + q];
#pragma unroll
        for (int q = 0; q < 8; q += 2) {
            uint32_t sel = half ? e8[q + 1] : e8[q];
            uint32_t u = xT[(size_t)(sel >> 1) * 32 + k];  // 128B/half-wave
            u ^= (sel & 1u) ? 0u : 0x80008000u;            // s=0 -> negate
            acc0 += __uint_as_float(u << 16);              // b = 2k
            acc1 += __uint_as_float(u & 0xffff0000u);      // b = 2k+1
        }
    }
    for (; base < n; base += 2) {
        uint32_t eA = e[base];
        uint32_t eB = (base + 1 < n) ? e[base + 1] : 0u;
        uint32_t sel   = half ? eB : eA;
        bool     valid = (base + (uint32_t)half) < n;
        uint32_t u = 0u;
        if (valid) {
            u = xT[(size_t)(sel >> 1) * 32 + k];
            u ^= (sel & 1u) ? 0u : 0x80008000u;
        }
        acc0 += __uint_as_float(u << 16);
        acc1 += __uint_as_float(u & 0xffff0000u);
    }
    acc0 += __shfl_xor(acc0, 32);
    acc1 += __shfl_xor(acc1, 32);
    if (half == 0) {
        obuf[2 * k + 0][w] = acc0;
        obuf[2 * k + 1][w] = acc1;
    }
    __syncthreads();
    // out: 64 rows x 16 p = one full 64B line per row
    if (t < 256) {
        const int b = t >> 2, q = t & 3;
        float4 vv;
        vv.x = obuf[b][4 * q + 0];
        vv.y = obuf[b][4 * q + 1];
        vv.z = obuf[b][4 * q + 2];
        vv.w = obuf[b][4 * q + 3];
        *reinterpret_cast<float4*>(
            &out[(size_t)b * PROJ + bucket * BUCKP + halfsel * 16 + 4 * q]) = vv;
    }
}

// ==================== R9 fallback: fused scatter + gather4 ==============
__global__ __launch_bounds__(256) void fused_tx_scatter(
    const float* __restrict__ x, const int* __restrict__ idx,
    const int* __restrict__ sgn, uint32_t* __restrict__ cnt,
    uint32_t* __restrict__ entries, uint32_t* __restrict__ xT)
{
    __shared__ float tile[64][65];
    const int d0 = blockIdx.x * 64;
    const int t  = threadIdx.x;

    const int e = (d0 << 2) + t;
    const int p = idx[e];
    const int s = sgn[e] & 1;

    const int c  = t & 15;
    const int r0 = t >> 4;
    float4 v[4];
#pragma unroll
    for (int it = 0; it < 4; ++it) {
        int b = it * 16 + r0;
        v[it] = *reinterpret_cast<const float4*>(&x[(size_t)b * DIM + d0 + 4 * c]);
    }
    {
        uint32_t dv   = ((uint32_t)(d0 + (t >> 2)) << 1) | (uint32_t)s;
        uint32_t slot = atomicAdd(&cnt[p], 1u);
        entries[(uint32_t)p * (uint32_t)CAP + slot] = dv;
    }
#pragma unroll
    for (int it = 0; it < 4; ++it) {
        int b = it * 16 + r0;
        tile[b][4 * c + 0] = v[it].x;
        tile[b][4 * c + 1] = v[it].y;
        tile[b][4 * c + 2] = v[it].z;
        tile[b][4 * c + 3] = v[it].w;
    }
    __syncthreads();
    const int a  = t & 7;
    const int dr = t >> 3;
#pragma unroll
    for (int pass = 0; pass < 2; ++pass) {
        const int dl = pass * 32 + dr;
        uint4 wv;
        uint32_t* wq = reinterpret_cast<uint32_t*>(&wv);
#pragma unroll
        for (int q = 0; q < 4; ++q) {
            const int k = 4 * a + q;
            uint32_t lo = f2bf(tile[2 * k + 0][dl] * 0.5f);
            uint32_t hi = f2bf(tile[2 * k + 1][dl] * 0.5f);
            wq[q] = lo | (hi << 16);
        }
        *reinterpret_cast<uint4*>(&xT[(size_t)(d0 + dl) * 32 + 4 * a]) = wv;
    }
}

__device__ __forceinline__ void proc8(const uint32_t* __restrict__ e,
    const uint32_t* __restrict__ xT, int half, int k,
    float& acc0, float& acc1)
{
#pragma unroll
    for (int t = 0; t < 8; t += 2) {
        uint32_t sel = half ? e[t + 1] : e[t];
        uint32_t u = xT[(size_t)(sel >> 1) * 32 + k];
        u ^= (sel & 1u) ? 0u : 0x80008000u;
        acc0 += __uint_as_float(u << 16);
        acc1 += __uint_as_float(u & 0xffff0000u);
    }
}

__global__ __launch_bounds__(1024) void gather4_kernel(
    const uint32_t* __restrict__ entries, const uint32_t* __restrict__ cnt,
    const uint32_t* __restrict__ xT, float* __restrict__ out)
{
    __shared__ float obuf[64][17];
    const int w    = threadIdx.x >> 6;
    const int lane = threadIdx.x & 63;
    const int p    = __builtin_amdgcn_readfirstlane(blockIdx.x * 16 + w);
    const uint32_t n  = __builtin_amdgcn_readfirstlane(cnt[p]);
    const uint32_t e0 = (uint32_t)p * (uint32_t)CAP;

    const int half = lane >> 5;
    const int k    = lane & 31;
    float acc0 = 0.f, acc1 = 0.f;

    uint32_t A[8], B[8];
    uint32_t base = 0;
    if (n >= 8) {
#pragma unroll
        for (int t = 0; t < 8; ++t) A[t] = entries[e0 + t];
    }
    for (; base + 24 <= n; base += 16) {
#pragma unroll
        for (int t = 0; t < 8; ++t) B[t] = entries[e0 + base + 8 + t];
        proc8(A, xT, half, k, acc0, acc1);
#pragma unroll
        for (int t = 0; t < 8; ++t) A[t] = entries[e0 + base + 16 + t];
        proc8(B, xT, half, k, acc0, acc1);
    }
    if (base + 16 <= n) {
#pragma unroll
        for (int t = 0; t < 8; ++t) B[t] = entries[e0 + base + 8 + t];
        proc8(A, xT, half, k, acc0, acc1);
        proc8(B, xT, half, k, acc0, acc1);
        base += 16;
    } else if (base + 8 <= n) {
        proc8(A, xT, half, k, acc0, acc1);
        base += 8;
    }
    for (; base < n; base += 2) {
        uint32_t eA = entries[e0 + base];
        uint32_t eB = (base + 1 < n) ? entries[e0 + base + 1] : 0u;
        uint32_t sel   = half ? eB : eA;
        bool     valid = (base + (uint32_t)half) < n;
        uint32_t u = 0u;
        if (valid) {
            u = xT[(size_t)(sel >> 1) * 32 + k];
            u ^= (sel & 1u) ? 0u : 0x80008000u;
        }
        acc0 += __uint_as_float(u << 16);
        acc1 += __uint_as_float(u & 0xffff0000u);
    }
    acc0 += __shfl_xor(acc0, 32);
    acc1 += __shfl_xor(acc1, 32);
    if (half == 0) {
        obuf[2 * k + 0][w] = acc0;
        obuf[2 * k + 1][w] = acc1;
    }
    __syncthreads();
    const int t = threadIdx.x;
    if (t < 256) {
        const int b = t >> 2, q = t & 3;
        float4 v;
        v.x = obuf[b][4 * q + 0];
        v.y = obuf[b][4 * q + 1];
        v.z = obuf[b][4 * q + 2];
        v.w = obuf[b][4 * q + 3];
        *reinterpret_cast<float4*>(&out[(size_t)b * PROJ + blockIdx.x * 16 + 4 * q]) = v;
    }
}

// ------------------------------------------------- fallback (R3 scatter)
__device__ __forceinline__ void lds_fadd(uint32_t byte_addr, float v) {
    asm volatile("ds_add_f32 %0, %1" :: "v"(byte_addr), "v"(v) : "memory");
}
__device__ __forceinline__ void lds_fadd_off32k(uint32_t byte_addr, float v) {
    asm volatile("ds_add_f32 %0, %1 offset:32768" :: "v"(byte_addr), "v"(v) : "memory");
}

__global__ __launch_bounds__(1024) void sjlt_scatter(
    const float* __restrict__ x, const int4* __restrict__ idx4,
    const int4* __restrict__ sgn4, float* __restrict__ out)
{
    __shared__ float acc[4 * PROJ];
    for (int i = threadIdx.x; i < 4 * PROJ; i += 1024) acc[i] = 0.0f;
    __syncthreads();
    const int row0 = blockIdx.y * 4;
    const int dbeg = blockIdx.x * (DIM / 16);
    const uint32_t accBase = (uint32_t)(uintptr_t)(&acc[0]);
    const float* xr0 = x + (size_t)(row0 + 0) * DIM;
    const float* xr1 = x + (size_t)(row0 + 1) * DIM;
    const float* xr2 = x + (size_t)(row0 + 2) * DIM;
    const float* xr3 = x + (size_t)(row0 + 3) * DIM;
    for (int d = dbeg + (int)threadIdx.x; d < dbeg + DIM / 16; d += 1024) {
        const int4 iv = idx4[d];
        const int4 sv = sgn4[d];
        const uint32_t u0 = __float_as_uint(xr0[d]);
        const uint32_t u1 = __float_as_uint(xr1[d]);
        const uint32_t u2 = __float_as_uint(xr2[d]);
        const uint32_t u3 = __float_as_uint(xr3[d]);
        const int p[4] = {iv.x, iv.y, iv.z, iv.w};
        const int s[4] = {sv.x, sv.y, sv.z, sv.w};
#pragma unroll
        for (int j = 0; j < 4; ++j) {
            const uint32_t flip = (uint32_t)(s[j] ^ 1) << 31;
            const uint32_t a01  = accBase + ((uint32_t)p[j] << 2);
            const uint32_t a23  = a01 + 2u * 32768u;
            lds_fadd        (a01, __uint_as_float(u0 ^ flip));
            lds_fadd_off32k (a01, __uint_as_float(u1 ^ flip));
            lds_fadd        (a23, __uint_as_float(u2 ^ flip));
            lds_fadd_off32k (a23, __uint_as_float(u3 ^ flip));
        }
    }
    __syncthreads();
    for (int i = threadIdx.x; i < 4 * PROJ; i += 1024) {
        const int r  = i >> 13;
        const int pp = i & (PROJ - 1);
        unsafeAtomicAdd(&out[(size_t)(row0 + r) * PROJ + pp], acc[i] * 0.5f);
    }
}

// --------------------------------------------------------------- launch
extern "C" void kernel_launch(void* const* d_in, const int* in_sizes, int n_in,
                              void* d_out, int out_size, void* d_ws, size_t ws_size,
                              hipStream_t stream) {
    const float* x   = (const float*)d_in[0];
    const int4*  idx = (const int4*) d_in[1];
    const int4*  sgn = (const int4*) d_in[2];
    float*       out = (float*)d_out;

    // R11 layout: cntAB[256*256] | coarse[256*256*80] | xT[DIM*32] = 88,342,528 B
    const size_t need_r11 = ((size_t)NBLKA * NBUCK
                           + (size_t)NBUCK * NBLKA * CAPB
                           + (size_t)DIM * 32) * 4;
    // R9 layout: cnt[PROJ] | entries[PROJ*CAP] | xT[DIM*32]       = 79,724,544 B
    const size_t need_r9  = ((size_t)PROJ + (size_t)PROJ * CAP + (size_t)DIM * 32) * 4;

    if (ws_size >= need_r11) {
        uint32_t* cntAB  = (uint32_t*)d_ws;
        uint32_t* coarse = cntAB + (size_t)NBLKA * NBUCK;
        uint32_t* xT     = coarse + (size_t)NBUCK * NBLKA * CAPB;

        // no memsets: cntAB fully written by binA; LDS counters zeroed
        // in-kernel; coarse padding beyond counts never read.
        transpose_kernel<<<DIM / 64,  256, 0, stream>>>(x, xT);
        binA_kernel     <<<NBLKA,     1024, 0, stream>>>(idx, sgn, cntAB, coarse);
        gather6_kernel  <<<NBUCK * 2, 1024, 0, stream>>>(coarse, cntAB, xT, out);
    } else if (ws_size >= need_r9) {
        uint32_t* cnt     = (uint32_t*)d_ws;
        uint32_t* entries = cnt + PROJ;
        uint32_t* xT      = entries + (size_t)PROJ * CAP;

        hipMemsetAsync(cnt, 0, PROJ * sizeof(uint32_t), stream);
        fused_tx_scatter<<<DIM / 64, 256, 0, stream>>>(
            x, (const int*)idx, (const int*)sgn, cnt, entries, xT);
        gather4_kernel<<<PROJ / 16, 1024, 0, stream>>>(entries, cnt, xT, out);
    } else {
        // ws too small: R3 LDS-scatter path (passes at ~830 us)
        hipMemsetAsync(d_out, 0, (size_t)out_size * sizeof(float), stream);
        dim3 grid(16, 16);
        sjlt_scatter<<<grid, 1024, 0, stream>>>(x, idx, sgn, out);
    }
}